// Round 1
// baseline (113.390 us; speedup 1.0000x reference)
//
#include <hip/hip_runtime.h>
#include <math.h>

#define WIN 11
#define HALF 5
#define SZ 32
#define BB 4
#define NG 16
#define NP 64
#define IH 640
#define IW 640
#define NPIX 3072   /* 3*32*32 */
#define SSIM_C1 6.5025f
#define SSIM_C2 58.5225f

__device__ __forceinline__ void gauss_weights(float* w) {
    float s = 0.f;
#pragma unroll
    for (int i = 0; i < WIN; ++i) {
        float x = (float)i - 5.0f;
        w[i] = expf(-x * x / 4.5f);
        s += w[i];
    }
    float inv = 1.0f / s;
#pragma unroll
    for (int i = 0; i < WIN; ++i) w[i] *= inv;
}

// ---------------- IoU / validity ----------------
__global__ __launch_bounds__(256) void k_valid(const float* __restrict__ gt,
                                               const float* __restrict__ pr,
                                               float* __restrict__ wv,
                                               float* __restrict__ acc) {
    int idx = blockIdx.x * blockDim.x + threadIdx.x;
    if (idx >= BB * NG * NP) return;
    int b = idx / (NG * NP);
    int r = idx % (NG * NP);
    int gi = r / NP, pi = r % NP;
    const float* g = gt + (b * NG + gi) * 4;
    const float* p = pr + (b * NP + pi) * 4;
    float gx = g[0], gy = g[1], gw = g[2], gh = g[3];
    float px = p[0], py = p[1], pw = p[2], ph = p[3];
    float tlx = fmaxf(gx - gw * 0.5f, px - pw * 0.5f);
    float tly = fmaxf(gy - gh * 0.5f, py - ph * 0.5f);
    float brx = fminf(gx + gw * 0.5f, px + pw * 0.5f);
    float bry = fminf(gy + gh * 0.5f, py + ph * 0.5f);
    float ag = gw * gh, ap = pw * ph;
    float en = ((tlx < brx) && (tly < bry)) ? 1.f : 0.f;
    float ai = (brx - tlx) * (bry - tly) * en;
    float iou = ai / (ag + ap - ai + 1e-16f);
    float v = (iou > 0.3f && pw > 2.f && ph > 2.f) ? 1.f : 0.f;
    wv[idx] = v;
    atomicAdd(&acc[0], v);   // compiler coalesces per-wave (G12)
}

// ---------------- crop-resize + per-crop mu/sigma ----------------
__global__ __launch_bounds__(256) void k_crop(const float* __restrict__ imgs,
                                              const float* __restrict__ gt,
                                              const float* __restrict__ pr,
                                              float* __restrict__ crops_g, float* __restrict__ mug,
                                              float* __restrict__ sigg,
                                              float* __restrict__ crops_p, float* __restrict__ mup,
                                              float* __restrict__ sigp) {
    int cid = blockIdx.x;  // 0..319
    int b;
    const float* box;
    float *dst, *mu, *sig;
    if (cid < BB * NG) {
        b = cid / NG;
        box = gt + cid * 4;
        dst = crops_g + cid * NPIX;
        mu = mug + cid * NPIX;
        sig = sigg + cid * NPIX;
    } else {
        int id = cid - BB * NG;
        b = id / NP;
        box = pr + id * 4;
        dst = crops_p + id * NPIX;
        mu = mup + id * NPIX;
        sig = sigp + id * NPIX;
    }

    __shared__ int s_ix0[SZ], s_ix1[SZ], s_iy0[SZ], s_iy1[SZ];
    __shared__ float s_fx[SZ], s_fy[SZ];
    __shared__ float cr[3][SZ][SZ];
    __shared__ float t1[3][SZ][SZ];
    __shared__ float t2[3][SZ][SZ];

    float cx = box[0], cy = box[1], bw = box[2], bh = box[3];
    float x0 = fminf(fmaxf(floorf(cx - bw * 0.5f), 0.f), (float)(IW - 1));
    float x1 = fminf(fmaxf(floorf(cx + bw * 0.5f), 0.f), (float)IW);
    float y0 = fminf(fmaxf(floorf(cy - bh * 0.5f), 0.f), (float)(IH - 1));
    float y1 = fminf(fmaxf(floorf(cy + bh * 0.5f), 0.f), (float)IH);
    float wp = fmaxf(x1 - x0, 1.f);
    float hp = fmaxf(y1 - y0, 1.f);
    int t = threadIdx.x;
    if (t < SZ) {
        float d = (float)t + 0.5f;
        float sx = x0 + fminf(fmaxf(d * wp / 32.f - 0.5f, 0.f), wp - 1.f);
        float flx = floorf(sx);
        s_ix0[t] = (int)flx;
        s_fx[t] = sx - flx;
        int xmax = (int)(x0 + wp - 1.f);
        s_ix1[t] = min((int)flx + 1, xmax);
        float sy = y0 + fminf(fmaxf(d * hp / 32.f - 0.5f, 0.f), hp - 1.f);
        float fly = floorf(sy);
        s_iy0[t] = (int)fly;
        s_fy[t] = sy - fly;
        int ymax = (int)(y0 + hp - 1.f);
        s_iy1[t] = min((int)fly + 1, ymax);
    }
    __syncthreads();

    const float* img = imgs + (size_t)b * 3 * IH * IW;
#pragma unroll
    for (int i = 0; i < 12; ++i) {
        int pidx = t + 256 * i;
        int c = pidx >> 10;
        int y = (pidx >> 5) & 31;
        int x = pidx & 31;
        const float* ic = img + c * IH * IW;
        int ix0 = s_ix0[x], ix1 = s_ix1[x], iy0 = s_iy0[y], iy1 = s_iy1[y];
        float fx = s_fx[x], fy = s_fy[y];
        float v00 = ic[iy0 * IW + ix0], v01 = ic[iy0 * IW + ix1];
        float v10 = ic[iy1 * IW + ix0], v11 = ic[iy1 * IW + ix1];
        float v = v00 * (1.f - fy) * (1.f - fx) + v01 * (1.f - fy) * fx +
                  v10 * fy * (1.f - fx) + v11 * fy * fx;
        cr[c][y][x] = v;
        dst[pidx] = v;
    }
    __syncthreads();

    float gw_[WIN];
    gauss_weights(gw_);
    // horizontal pass on x and x^2
#pragma unroll
    for (int i = 0; i < 12; ++i) {
        int pidx = t + 256 * i;
        int c = pidx >> 10, y = (pidx >> 5) & 31, x = pidx & 31;
        float a1 = 0.f, a2 = 0.f;
#pragma unroll
        for (int k = 0; k < WIN; ++k) {
            int xx = x + k - HALF;
            if (xx >= 0 && xx < SZ) {
                float v = cr[c][y][xx];
                a1 += gw_[k] * v;
                a2 += gw_[k] * v * v;
            }
        }
        t1[c][y][x] = a1;
        t2[c][y][x] = a2;
    }
    __syncthreads();
    // vertical pass
#pragma unroll
    for (int i = 0; i < 12; ++i) {
        int pidx = t + 256 * i;
        int c = pidx >> 10, y = (pidx >> 5) & 31, x = pidx & 31;
        float a1 = 0.f, a2 = 0.f;
#pragma unroll
        for (int k = 0; k < WIN; ++k) {
            int yy = y + k - HALF;
            if (yy >= 0 && yy < SZ) {
                a1 += gw_[k] * t1[c][yy][x];
                a2 += gw_[k] * t2[c][yy][x];
            }
        }
        mu[pidx] = a1;
        sig[pidx] = a2 - a1 * a1;
    }
}

// ---------------- per-pair SSIM + L1 ----------------
__global__ __launch_bounds__(256) void k_pair(const float* __restrict__ crops_g,
                                              const float* __restrict__ mug,
                                              const float* __restrict__ sigg,
                                              const float* __restrict__ crops_p,
                                              const float* __restrict__ mup,
                                              const float* __restrict__ sigp,
                                              const float* __restrict__ wv,
                                              float* __restrict__ acc) {
    int pid = blockIdx.x;  // 0..4095
    float w = wv[pid];
    if (w == 0.f) return;  // wave-uniform early exit, before any barrier
    int b = pid / (NG * NP);
    int r = pid % (NG * NP);
    int gi = r / NP, pi = r % NP;
    const float* g = crops_g + (b * NG + gi) * NPIX;
    const float* p = crops_p + (b * NP + pi) * NPIX;
    const float* mg = mug + (b * NG + gi) * NPIX;
    const float* sg = sigg + (b * NG + gi) * NPIX;
    const float* mp = mup + (b * NP + pi) * NPIX;
    const float* sp = sigp + (b * NP + pi) * NPIX;

    __shared__ float gp[3][SZ][SZ];
    __shared__ float tmp[3][SZ][SZ];
    __shared__ float rl[4], rs[4];

    int t = threadIdx.x;
    float l1 = 0.f;
#pragma unroll
    for (int i = 0; i < 12; ++i) {
        int pidx = t + 256 * i;
        int c = pidx >> 10, y = (pidx >> 5) & 31, x = pidx & 31;
        float gv = g[pidx], pv = p[pidx];
        gp[c][y][x] = gv * pv;
        l1 += fabsf(gv - pv);
    }
    __syncthreads();

    float gw_[WIN];
    gauss_weights(gw_);
#pragma unroll
    for (int i = 0; i < 12; ++i) {
        int pidx = t + 256 * i;
        int c = pidx >> 10, y = (pidx >> 5) & 31, x = pidx & 31;
        float a = 0.f;
#pragma unroll
        for (int k = 0; k < WIN; ++k) {
            int xx = x + k - HALF;
            if (xx >= 0 && xx < SZ) a += gw_[k] * gp[c][y][xx];
        }
        tmp[c][y][x] = a;
    }
    __syncthreads();

    float ss = 0.f;
#pragma unroll
    for (int i = 0; i < 12; ++i) {
        int pidx = t + 256 * i;
        int c = pidx >> 10, y = (pidx >> 5) & 31, x = pidx & 31;
        float a = 0.f;
#pragma unroll
        for (int k = 0; k < WIN; ++k) {
            int yy = y + k - HALF;
            if (yy >= 0 && yy < SZ) a += gw_[k] * tmp[c][yy][x];
        }
        float m1 = mg[pidx], m2 = mp[pidx];
        float sgp = a - m1 * m2;
        float num = (2.f * m1 * m2 + SSIM_C1) * (2.f * sgp + SSIM_C2);
        float den = (m1 * m1 + m2 * m2 + SSIM_C1) * (sg[pidx] + sp[pidx] + SSIM_C2);
        ss += num / den;
    }

    // block reduction: wave shuffle then LDS across 4 waves
#pragma unroll
    for (int off = 32; off > 0; off >>= 1) {
        l1 += __shfl_down(l1, off);
        ss += __shfl_down(ss, off);
    }
    int wave = t >> 6, lane = t & 63;
    if (lane == 0) { rl[wave] = l1; rs[wave] = ss; }
    __syncthreads();
    if (t == 0) {
        float L = rl[0] + rl[1] + rl[2] + rl[3];
        float S = rs[0] + rs[1] + rs[2] + rs[3];
        atomicAdd(&acc[1], w * L * (1.0f / (255.0f * (float)NPIX)));
        atomicAdd(&acc[2], w * S * (1.0f / (float)NPIX));
    }
}

// ---------------- finalize ----------------
__global__ void k_final(const float* __restrict__ acc, float* __restrict__ out) {
    float cnt = acc[0], l1 = acc[1], ss = acc[2];
    float m = fmaxf(cnt, 1.f);
    float loss = l1 / m + 1.f - ss / m;
    out[0] = (cnt > 0.f) ? loss : 0.f;
}

extern "C" void kernel_launch(void* const* d_in, const int* in_sizes, int n_in,
                              void* d_out, int out_size, void* d_ws, size_t ws_size,
                              hipStream_t stream) {
    const float* imgs = (const float*)d_in[0];  // (4,3,640,640)
    const float* gt = (const float*)d_in[1];    // (4,16,4)
    const float* pr = (const float*)d_in[2];    // (4,64,4)

    float* ws = (float*)d_ws;
    float* wv = ws;                     // 4096
    float* acc = ws + 4096;             // 4: cnt, l1_sum, ssim_sum
    float* cg = ws + 4352;              // 64*3072
    float* mg = cg + 196608;
    float* sg = mg + 196608;
    float* cp = sg + 196608;            // 256*3072
    float* mp = cp + 786432;
    float* sp = mp + 786432;

    hipMemsetAsync(acc, 0, 4 * sizeof(float), stream);
    k_valid<<<16, 256, 0, stream>>>(gt, pr, wv, acc);
    k_crop<<<320, 256, 0, stream>>>(imgs, gt, pr, cg, mg, sg, cp, mp, sp);
    k_pair<<<BB * NG * NP, 256, 0, stream>>>(cg, mg, sg, cp, mp, sp, wv, acc);
    k_final<<<1, 1, 0, stream>>>(acc, (float*)d_out);
}

// Round 2
// 108.778 us; speedup vs baseline: 1.0424x; 1.0424x over previous
//
#include <hip/hip_runtime.h>
#include <math.h>

#define WIN 11
#define HALF 5
#define SZ 32
#define PST 33          /* padded LDS row stride */
#define BB 4
#define NG 16
#define NP 64
#define IH 640
#define IW 640
#define CPIX 1024       /* 32*32 per channel */
#define NPIX 3072       /* 3*32*32 per crop */
#define NCROP 320       /* 64 gt + 256 pred */
#define SSIM_C1 6.5025f
#define SSIM_C2 58.5225f

// exp(-(i-5)^2/4.5)/sum — 11-tap Gaussian, sigma=1.5, compile-time
#define GW_INIT {0.001028379f, 0.007598757f, 0.036000791f, 0.109360748f, \
                 0.213005174f, 0.266011868f, 0.213005174f, 0.109360748f, \
                 0.036000791f, 0.007598757f, 0.001028379f}

// ---------------- crop-resize + per-crop mu/sigma, one block per (crop, channel) ----------------
__global__ __launch_bounds__(256) void k_crop(const float* __restrict__ imgs,
                                              const float* __restrict__ gt,
                                              const float* __restrict__ pr,
                                              float* __restrict__ crops,
                                              float* __restrict__ mus,
                                              float* __restrict__ sigs) {
    const int c = blockIdx.x;      // 0..2
    const int crop = blockIdx.y;   // 0..319 (0..63 gt, 64..319 pred)
    int b;
    const float* box;
    if (crop < BB * NG) {
        b = crop >> 4;
        box = gt + crop * 4;
    } else {
        int id = crop - BB * NG;
        b = id >> 6;
        box = pr + id * 4;
    }

    __shared__ float s_fx[SZ], s_fy[SZ];
    __shared__ int s_ix0[SZ], s_ix1[SZ], s_iy0[SZ], s_iy1[SZ];
    __shared__ float cr[SZ][PST];
    __shared__ float t1[SZ][PST];
    __shared__ float t2[SZ][PST];

    const int t = threadIdx.x;
    if (t < SZ) {
        float cx = box[0], cy = box[1], bw = box[2], bh = box[3];
        float x0 = fminf(fmaxf(floorf(cx - bw * 0.5f), 0.f), (float)(IW - 1));
        float x1 = fminf(fmaxf(floorf(cx + bw * 0.5f), 0.f), (float)IW);
        float y0 = fminf(fmaxf(floorf(cy - bh * 0.5f), 0.f), (float)(IH - 1));
        float y1 = fminf(fmaxf(floorf(cy + bh * 0.5f), 0.f), (float)IH);
        float wp = fmaxf(x1 - x0, 1.f);
        float hp = fmaxf(y1 - y0, 1.f);
        float d = (float)t + 0.5f;
        float sx = x0 + fminf(fmaxf(d * wp * (1.f / 32.f) - 0.5f, 0.f), wp - 1.f);
        float flx = floorf(sx);
        s_ix0[t] = (int)flx;
        s_fx[t] = sx - flx;
        s_ix1[t] = min((int)flx + 1, (int)(x0 + wp - 1.f));
        float sy = y0 + fminf(fmaxf(d * hp * (1.f / 32.f) - 0.5f, 0.f), hp - 1.f);
        float fly = floorf(sy);
        s_iy0[t] = (int)fly;
        s_fy[t] = sy - fly;
        s_iy1[t] = min((int)fly + 1, (int)(y0 + hp - 1.f));
    }
    __syncthreads();

    const float* ic = imgs + ((size_t)b * 3 + c) * IH * IW;
    const int y = t >> 3;          // thread owns pixels 4t..4t+3 (same row)
    const int xb = (t & 7) * 4;
    const float fy = s_fy[y];
    const float* r0 = ic + s_iy0[y] * IW;
    const float* r1 = ic + s_iy1[y] * IW;
    float vv[4];
#pragma unroll
    for (int j = 0; j < 4; ++j) {
        int x = xb + j;
        int ix0 = s_ix0[x], ix1 = s_ix1[x];
        float fx = s_fx[x];
        float v00 = r0[ix0], v01 = r0[ix1], v10 = r1[ix0], v11 = r1[ix1];
        float v = v00 * (1.f - fy) * (1.f - fx) + v01 * (1.f - fy) * fx +
                  v10 * fy * (1.f - fx) + v11 * fy * fx;
        vv[j] = v;
        cr[y][x] = v;
    }
    float* dst = crops + (size_t)crop * NPIX + c * CPIX + t * 4;
    *(float4*)dst = make_float4(vv[0], vv[1], vv[2], vv[3]);
    __syncthreads();

    constexpr float GW[WIN] = GW_INIT;
    // horizontal pass on x and x^2
#pragma unroll
    for (int j = 0; j < 4; ++j) {
        int x = xb + j;
        float a1 = 0.f, a2 = 0.f;
#pragma unroll
        for (int k = 0; k < WIN; ++k) {
            int xx = x + k - HALF;
            if (xx >= 0 && xx < SZ) {
                float v = cr[y][xx];
                a1 += GW[k] * v;
                a2 += GW[k] * v * v;
            }
        }
        t1[y][x] = a1;
        t2[y][x] = a2;
    }
    __syncthreads();
    // vertical pass
    float m[4], s[4];
#pragma unroll
    for (int j = 0; j < 4; ++j) {
        int x = xb + j;
        float a1 = 0.f, a2 = 0.f;
#pragma unroll
        for (int k = 0; k < WIN; ++k) {
            int yy = y + k - HALF;
            if (yy >= 0 && yy < SZ) {
                a1 += GW[k] * t1[yy][x];
                a2 += GW[k] * t2[yy][x];
            }
        }
        m[j] = a1;
        s[j] = a2 - a1 * a1;
    }
    float* mdst = mus + (size_t)crop * NPIX + c * CPIX + t * 4;
    float* sdst = sigs + (size_t)crop * NPIX + c * CPIX + t * 4;
    *(float4*)mdst = make_float4(m[0], m[1], m[2], m[3]);
    *(float4*)sdst = make_float4(s[0], s[1], s[2], s[3]);
}

// ---------------- per-(pair, channel) SSIM + L1 with fused validity ----------------
__global__ __launch_bounds__(256) void k_pair(const float* __restrict__ gt,
                                              const float* __restrict__ pr,
                                              const float* __restrict__ crops,
                                              const float* __restrict__ mus,
                                              const float* __restrict__ sigs,
                                              float* __restrict__ acc) {
    const int c = blockIdx.x;      // 0..2
    const int pair = blockIdx.y;   // 0..4095
    const int b = pair >> 10;
    const int r = pair & 1023;
    const int gi = r >> 6, pi = r & 63;

    // validity (wave-uniform; boxes are tiny + L2-resident)
    const float* g = gt + (b * NG + gi) * 4;
    const float* p = pr + (b * NP + pi) * 4;
    float gx = g[0], gy = g[1], gw = g[2], gh = g[3];
    float px = p[0], py = p[1], pw = p[2], ph = p[3];
    float tlx = fmaxf(gx - gw * 0.5f, px - pw * 0.5f);
    float tly = fmaxf(gy - gh * 0.5f, py - ph * 0.5f);
    float brx = fminf(gx + gw * 0.5f, px + pw * 0.5f);
    float bry = fminf(gy + gh * 0.5f, py + ph * 0.5f);
    float en = ((tlx < brx) && (tly < bry)) ? 1.f : 0.f;
    float ai = (brx - tlx) * (bry - tly) * en;
    float iou = ai / (gw * gh + pw * ph - ai + 1e-16f);
    if (!(iou > 0.3f && pw > 2.f && ph > 2.f)) return;

    const int gcrop = b * NG + gi;
    const int pcrop = BB * NG + b * NP + pi;
    const size_t goff = (size_t)gcrop * NPIX + c * CPIX;
    const size_t poff = (size_t)pcrop * NPIX + c * CPIX;

    __shared__ float gp[SZ][PST];
    __shared__ float tmp[SZ][PST];
    __shared__ float rl[4], rs[4];

    const int t = threadIdx.x;
    const int y = t >> 3;
    const int xb = (t & 7) * 4;

    float4 gv = *(const float4*)(crops + goff + t * 4);
    float4 pv = *(const float4*)(crops + poff + t * 4);
    float l1 = fabsf(gv.x - pv.x) + fabsf(gv.y - pv.y) +
               fabsf(gv.z - pv.z) + fabsf(gv.w - pv.w);
    gp[y][xb + 0] = gv.x * pv.x;
    gp[y][xb + 1] = gv.y * pv.y;
    gp[y][xb + 2] = gv.z * pv.z;
    gp[y][xb + 3] = gv.w * pv.w;
    __syncthreads();

    constexpr float GW[WIN] = GW_INIT;
#pragma unroll
    for (int j = 0; j < 4; ++j) {
        int x = xb + j;
        float a = 0.f;
#pragma unroll
        for (int k = 0; k < WIN; ++k) {
            int xx = x + k - HALF;
            if (xx >= 0 && xx < SZ) a += GW[k] * gp[y][xx];
        }
        tmp[y][x] = a;
    }
    __syncthreads();

    float4 mg = *(const float4*)(mus + goff + t * 4);
    float4 mp = *(const float4*)(mus + poff + t * 4);
    float4 sg = *(const float4*)(sigs + goff + t * 4);
    float4 sp = *(const float4*)(sigs + poff + t * 4);
    float mgv[4] = {mg.x, mg.y, mg.z, mg.w};
    float mpv[4] = {mp.x, mp.y, mp.z, mp.w};
    float sgv[4] = {sg.x, sg.y, sg.z, sg.w};
    float spv[4] = {sp.x, sp.y, sp.z, sp.w};
    float ss = 0.f;
#pragma unroll
    for (int j = 0; j < 4; ++j) {
        int x = xb + j;
        float a = 0.f;
#pragma unroll
        for (int k = 0; k < WIN; ++k) {
            int yy = y + k - HALF;
            if (yy >= 0 && yy < SZ) a += GW[k] * tmp[yy][x];
        }
        float m1 = mgv[j], m2 = mpv[j];
        float sgp = a - m1 * m2;
        float num = (2.f * m1 * m2 + SSIM_C1) * (2.f * sgp + SSIM_C2);
        float den = (m1 * m1 + m2 * m2 + SSIM_C1) * (sgv[j] + spv[j] + SSIM_C2);
        ss += num / den;
    }

    // block reduction: 64-lane shuffle, then LDS across 4 waves
#pragma unroll
    for (int off = 32; off > 0; off >>= 1) {
        l1 += __shfl_down(l1, off);
        ss += __shfl_down(ss, off);
    }
    const int wave = t >> 6, lane = t & 63;
    if (lane == 0) { rl[wave] = l1; rs[wave] = ss; }
    __syncthreads();
    if (t == 0) {
        float L = rl[0] + rl[1] + rl[2] + rl[3];
        float S = rs[0] + rs[1] + rs[2] + rs[3];
        atomicAdd(&acc[1], L * (1.0f / (255.0f * (float)NPIX)));
        atomicAdd(&acc[2], S * (1.0f / (float)NPIX));
        if (c == 0) atomicAdd(&acc[0], 1.f);
    }
}

// ---------------- finalize ----------------
__global__ void k_final(const float* __restrict__ acc, float* __restrict__ out) {
    float cnt = acc[0], l1 = acc[1], ss = acc[2];
    float m = fmaxf(cnt, 1.f);
    float loss = l1 / m + 1.f - ss / m;
    out[0] = (cnt > 0.f) ? loss : 0.f;
}

extern "C" void kernel_launch(void* const* d_in, const int* in_sizes, int n_in,
                              void* d_out, int out_size, void* d_ws, size_t ws_size,
                              hipStream_t stream) {
    const float* imgs = (const float*)d_in[0];  // (4,3,640,640)
    const float* gt = (const float*)d_in[1];    // (4,16,4)
    const float* pr = (const float*)d_in[2];    // (4,64,4)

    float* ws = (float*)d_ws;
    float* crops = ws;                                  // 320*3072
    float* mus = crops + (size_t)NCROP * NPIX;
    float* sigs = mus + (size_t)NCROP * NPIX;
    float* acc = sigs + (size_t)NCROP * NPIX;           // 3: cnt, l1_sum, ssim_sum

    hipMemsetAsync(acc, 0, 4 * sizeof(float), stream);
    k_crop<<<dim3(3, NCROP), 256, 0, stream>>>(imgs, gt, pr, crops, mus, sigs);
    k_pair<<<dim3(3, BB * NG * NP), 256, 0, stream>>>(gt, pr, crops, mus, sigs, acc);
    k_final<<<1, 1, 0, stream>>>(acc, (float*)d_out);
}

// Round 3
// 91.406 us; speedup vs baseline: 1.2405x; 1.1901x over previous
//
#include <hip/hip_runtime.h>
#include <math.h>

#define WIN 11
#define HALF 5
#define SZ 32
#define PST 33          /* padded LDS row stride */
#define BB 4
#define NG 16
#define NP 64
#define IH 640
#define IW 640
#define CPIX 1024       /* 32*32 per channel */
#define NPIX 3072       /* 3*32*32 per crop */
#define NCROP 320       /* 64 gt + 256 pred */
#define NPAIR 4096      /* 4*16*64 */
#define NSLOT 512       /* k_pair blocks per channel; grid-stride covers count>NSLOT */
#define SSIM_C1 6.5025f
#define SSIM_C2 58.5225f

// exp(-(i-5)^2/4.5)/sum — 11-tap Gaussian, sigma=1.5, compile-time
#define GW_INIT {0.001028379f, 0.007598757f, 0.036000791f, 0.109360748f, \
                 0.213005174f, 0.266011868f, 0.213005174f, 0.109360748f, \
                 0.036000791f, 0.007598757f, 0.001028379f}

// ---------------- validity -> compact list ----------------
__global__ __launch_bounds__(256) void k_valid(const float* __restrict__ gt,
                                               const float* __restrict__ pr,
                                               int* __restrict__ list,
                                               int* __restrict__ count) {
    int idx = blockIdx.x * 256 + threadIdx.x;  // 0..4095
    int b = idx >> 10;
    int r = idx & 1023;
    int gi = r >> 6, pi = r & 63;
    const float* g = gt + (b * NG + gi) * 4;
    const float* p = pr + (b * NP + pi) * 4;
    float gx = g[0], gy = g[1], gw = g[2], gh = g[3];
    float px = p[0], py = p[1], pw = p[2], ph = p[3];
    float tlx = fmaxf(gx - gw * 0.5f, px - pw * 0.5f);
    float tly = fmaxf(gy - gh * 0.5f, py - ph * 0.5f);
    float brx = fminf(gx + gw * 0.5f, px + pw * 0.5f);
    float bry = fminf(gy + gh * 0.5f, py + ph * 0.5f);
    float en = ((tlx < brx) && (tly < bry)) ? 1.f : 0.f;
    float ai = (brx - tlx) * (bry - tly) * en;
    float iou = ai / (gw * gh + pw * ph - ai + 1e-16f);
    if (iou > 0.3f && pw > 2.f && ph > 2.f) {
        int s = atomicAdd(count, 1);   // wave-coalesced by compiler (G12)
        list[s] = idx;
    }
}

// ---------------- crop-resize + per-crop mu/sigma, one block per (channel, crop) ----------------
__global__ __launch_bounds__(256) void k_crop(const float* __restrict__ imgs,
                                              const float* __restrict__ gt,
                                              const float* __restrict__ pr,
                                              float* __restrict__ crops,
                                              float* __restrict__ mus,
                                              float* __restrict__ sigs) {
    const int c = blockIdx.x;      // 0..2
    const int crop = blockIdx.y;   // 0..319 (0..63 gt, 64..319 pred)
    int b;
    const float* box;
    if (crop < BB * NG) {
        b = crop >> 4;
        box = gt + crop * 4;
    } else {
        int id = crop - BB * NG;
        b = id >> 6;
        box = pr + id * 4;
    }

    __shared__ float s_fx[SZ], s_fy[SZ];
    __shared__ int s_ix0[SZ], s_ix1[SZ], s_iy0[SZ], s_iy1[SZ];
    __shared__ float cr[SZ][PST];
    __shared__ float t1[SZ][PST];
    __shared__ float t2[SZ][PST];

    const int t = threadIdx.x;
    if (t < SZ) {
        float cx = box[0], cy = box[1], bw = box[2], bh = box[3];
        float x0 = fminf(fmaxf(floorf(cx - bw * 0.5f), 0.f), (float)(IW - 1));
        float x1 = fminf(fmaxf(floorf(cx + bw * 0.5f), 0.f), (float)IW);
        float y0 = fminf(fmaxf(floorf(cy - bh * 0.5f), 0.f), (float)(IH - 1));
        float y1 = fminf(fmaxf(floorf(cy + bh * 0.5f), 0.f), (float)IH);
        float wp = fmaxf(x1 - x0, 1.f);
        float hp = fmaxf(y1 - y0, 1.f);
        float d = (float)t + 0.5f;
        float sx = x0 + fminf(fmaxf(d * wp * (1.f / 32.f) - 0.5f, 0.f), wp - 1.f);
        float flx = floorf(sx);
        s_ix0[t] = (int)flx;
        s_fx[t] = sx - flx;
        s_ix1[t] = min((int)flx + 1, (int)(x0 + wp - 1.f));
        float sy = y0 + fminf(fmaxf(d * hp * (1.f / 32.f) - 0.5f, 0.f), hp - 1.f);
        float fly = floorf(sy);
        s_iy0[t] = (int)fly;
        s_fy[t] = sy - fly;
        s_iy1[t] = min((int)fly + 1, (int)(y0 + hp - 1.f));
    }
    __syncthreads();

    const float* ic = imgs + ((size_t)b * 3 + c) * IH * IW;
    const int y = t >> 3;          // thread owns pixels 4t..4t+3 (same row)
    const int xb = (t & 7) * 4;
    const float fy = s_fy[y];
    const float* r0 = ic + s_iy0[y] * IW;
    const float* r1 = ic + s_iy1[y] * IW;
    float vv[4];
#pragma unroll
    for (int j = 0; j < 4; ++j) {
        int x = xb + j;
        int ix0 = s_ix0[x], ix1 = s_ix1[x];
        float fx = s_fx[x];
        float v00 = r0[ix0], v01 = r0[ix1], v10 = r1[ix0], v11 = r1[ix1];
        float v = v00 * (1.f - fy) * (1.f - fx) + v01 * (1.f - fy) * fx +
                  v10 * fy * (1.f - fx) + v11 * fy * fx;
        vv[j] = v;
        cr[y][x] = v;
    }
    float* dst = crops + (size_t)crop * NPIX + c * CPIX + t * 4;
    *(float4*)dst = make_float4(vv[0], vv[1], vv[2], vv[3]);
    __syncthreads();

    constexpr float GW[WIN] = GW_INIT;
    // horizontal pass on x and x^2
#pragma unroll
    for (int j = 0; j < 4; ++j) {
        int x = xb + j;
        float a1 = 0.f, a2 = 0.f;
#pragma unroll
        for (int k = 0; k < WIN; ++k) {
            int xx = x + k - HALF;
            if (xx >= 0 && xx < SZ) {
                float v = cr[y][xx];
                a1 += GW[k] * v;
                a2 += GW[k] * v * v;
            }
        }
        t1[y][x] = a1;
        t2[y][x] = a2;
    }
    __syncthreads();
    // vertical pass
    float m[4], s[4];
#pragma unroll
    for (int j = 0; j < 4; ++j) {
        int x = xb + j;
        float a1 = 0.f, a2 = 0.f;
#pragma unroll
        for (int k = 0; k < WIN; ++k) {
            int yy = y + k - HALF;
            if (yy >= 0 && yy < SZ) {
                a1 += GW[k] * t1[yy][x];
                a2 += GW[k] * t2[yy][x];
            }
        }
        m[j] = a1;
        s[j] = a2 - a1 * a1;
    }
    float* mdst = mus + (size_t)crop * NPIX + c * CPIX + t * 4;
    float* sdst = sigs + (size_t)crop * NPIX + c * CPIX + t * 4;
    *(float4*)mdst = make_float4(m[0], m[1], m[2], m[3]);
    *(float4*)sdst = make_float4(s[0], s[1], s[2], s[3]);
}

// ---------------- per-(valid-pair, channel) SSIM + L1 via compact list ----------------
__global__ __launch_bounds__(256) void k_pair(const int* __restrict__ list,
                                              const int* __restrict__ count,
                                              const float* __restrict__ crops,
                                              const float* __restrict__ mus,
                                              const float* __restrict__ sigs,
                                              float* __restrict__ pairL1,
                                              float* __restrict__ pairSS) {
    const int c = blockIdx.x;      // 0..2
    const int n = *count;
    const int t = threadIdx.x;
    const int y = t >> 3;
    const int xb = (t & 7) * 4;

    __shared__ float gp[SZ][PST];
    __shared__ float tmp[SZ][PST];
    __shared__ float rl[4], rs[4];
    constexpr float GW[WIN] = GW_INIT;

    for (int slot = blockIdx.y; slot < n; slot += NSLOT) {
        const int pair = list[slot];
        const int b = pair >> 10;
        const int r = pair & 1023;
        const int gi = r >> 6, pi = r & 63;
        const size_t goff = (size_t)(b * NG + gi) * NPIX + c * CPIX;
        const size_t poff = (size_t)(BB * NG + b * NP + pi) * NPIX + c * CPIX;

        float4 gv = *(const float4*)(crops + goff + t * 4);
        float4 pv = *(const float4*)(crops + poff + t * 4);
        // hoist mu/sigma loads: in flight across both conv phases
        float4 mg = *(const float4*)(mus + goff + t * 4);
        float4 mp = *(const float4*)(mus + poff + t * 4);
        float4 sg = *(const float4*)(sigs + goff + t * 4);
        float4 sp = *(const float4*)(sigs + poff + t * 4);

        float l1 = fabsf(gv.x - pv.x) + fabsf(gv.y - pv.y) +
                   fabsf(gv.z - pv.z) + fabsf(gv.w - pv.w);
        gp[y][xb + 0] = gv.x * pv.x;
        gp[y][xb + 1] = gv.y * pv.y;
        gp[y][xb + 2] = gv.z * pv.z;
        gp[y][xb + 3] = gv.w * pv.w;
        __syncthreads();

#pragma unroll
        for (int j = 0; j < 4; ++j) {
            int x = xb + j;
            float a = 0.f;
#pragma unroll
            for (int k = 0; k < WIN; ++k) {
                int xx = x + k - HALF;
                if (xx >= 0 && xx < SZ) a += GW[k] * gp[y][xx];
            }
            tmp[y][x] = a;
        }
        __syncthreads();

        float mgv[4] = {mg.x, mg.y, mg.z, mg.w};
        float mpv[4] = {mp.x, mp.y, mp.z, mp.w};
        float sgv[4] = {sg.x, sg.y, sg.z, sg.w};
        float spv[4] = {sp.x, sp.y, sp.z, sp.w};
        float ss = 0.f;
#pragma unroll
        for (int j = 0; j < 4; ++j) {
            int x = xb + j;
            float a = 0.f;
#pragma unroll
            for (int k = 0; k < WIN; ++k) {
                int yy = y + k - HALF;
                if (yy >= 0 && yy < SZ) a += GW[k] * tmp[yy][x];
            }
            float m1 = mgv[j], m2 = mpv[j];
            float sgp = a - m1 * m2;
            float num = (2.f * m1 * m2 + SSIM_C1) * (2.f * sgp + SSIM_C2);
            float den = (m1 * m1 + m2 * m2 + SSIM_C1) * (sgv[j] + spv[j] + SSIM_C2);
            ss += num / den;
        }

        // block reduction: 64-lane shuffle, then LDS across 4 waves
#pragma unroll
        for (int off = 32; off > 0; off >>= 1) {
            l1 += __shfl_down(l1, off);
            ss += __shfl_down(ss, off);
        }
        const int wave = t >> 6, lane = t & 63;
        if (lane == 0) { rl[wave] = l1; rs[wave] = ss; }
        __syncthreads();
        if (t == 0) {
            pairL1[slot * 3 + c] = rl[0] + rl[1] + rl[2] + rl[3];
            pairSS[slot * 3 + c] = rs[0] + rs[1] + rs[2] + rs[3];
        }
        // next-iter gp-fill barrier orders LDS reuse; no extra barrier needed
    }
}

// ---------------- finalize: deterministic reduction over compact results ----------------
__global__ __launch_bounds__(256) void k_final(const int* __restrict__ count,
                                               const float* __restrict__ pairL1,
                                               const float* __restrict__ pairSS,
                                               float* __restrict__ out) {
    const int n3 = (*count) * 3;
    const int t = threadIdx.x;
    float L = 0.f, S = 0.f;
    for (int i = t; i < n3; i += 256) {
        L += pairL1[i];
        S += pairSS[i];
    }
    __shared__ float rl[4], rs[4];
#pragma unroll
    for (int off = 32; off > 0; off >>= 1) {
        L += __shfl_down(L, off);
        S += __shfl_down(S, off);
    }
    const int wave = t >> 6, lane = t & 63;
    if (lane == 0) { rl[wave] = L; rs[wave] = S; }
    __syncthreads();
    if (t == 0) {
        float cnt = (float)(*count);
        float Lt = (rl[0] + rl[1] + rl[2] + rl[3]) * (1.0f / (255.0f * (float)NPIX));
        float St = (rs[0] + rs[1] + rs[2] + rs[3]) * (1.0f / (float)NPIX);
        float m = fmaxf(cnt, 1.f);
        float loss = Lt / m + 1.f - St / m;
        out[0] = (cnt > 0.f) ? loss : 0.f;
    }
}

extern "C" void kernel_launch(void* const* d_in, const int* in_sizes, int n_in,
                              void* d_out, int out_size, void* d_ws, size_t ws_size,
                              hipStream_t stream) {
    const float* imgs = (const float*)d_in[0];  // (4,3,640,640)
    const float* gt = (const float*)d_in[1];    // (4,16,4)
    const float* pr = (const float*)d_in[2];    // (4,64,4)

    float* ws = (float*)d_ws;
    float* crops = ws;                                   // 320*3072
    float* mus = crops + (size_t)NCROP * NPIX;
    float* sigs = mus + (size_t)NCROP * NPIX;
    float* pairL1 = sigs + (size_t)NCROP * NPIX;         // 4096*3
    float* pairSS = pairL1 + (size_t)NPAIR * 3;          // 4096*3
    int* list = (int*)(pairSS + (size_t)NPAIR * 3);      // 4096
    int* count = list + NPAIR;                           // 1

    hipMemsetAsync(count, 0, sizeof(int), stream);
    k_valid<<<NPAIR / 256, 256, 0, stream>>>(gt, pr, list, count);
    k_crop<<<dim3(3, NCROP), 256, 0, stream>>>(imgs, gt, pr, crops, mus, sigs);
    k_pair<<<dim3(3, NSLOT), 256, 0, stream>>>(list, count, crops, mus, sigs, pairL1, pairSS);
    k_final<<<1, 256, 0, stream>>>(count, pairL1, pairSS, (float*)d_out);
}